// Round 5
// baseline (1389.976 us; speedup 1.0000x reference)
//
#include <hip/hip_runtime.h>

#define BATCH 4096
#define FEAT 41920
#define HACC 256
#define H1 32
#define H2 32

typedef unsigned int u32x4 __attribute__((ext_vector_type(4)));  // native vec: OK for nontemporal builtins

// ---------------------------------------------------------------------------
// Transpose W [HACC x FEAT] -> WT [FEAT x HACC], both sides in one launch.
// grid: (FEAT/32, HACC/32, 2), block: (32, 8).  z=0: white, z=1: black.
// ---------------------------------------------------------------------------
__global__ __launch_bounds__(256) void transpose_kernel(
    const float* __restrict__ Ww, float* __restrict__ WwT,
    const float* __restrict__ Wb, float* __restrict__ WbT)
{
    const float* W  = blockIdx.z ? Wb  : Ww;
    float*       WT = blockIdx.z ? WbT : WwT;
    __shared__ float tile[32][33];              // +1 pad: conflict-free
    const int fBase = blockIdx.x * 32;
    const int hBase = blockIdx.y * 32;
    const int tx = threadIdx.x;                 // 0..31
    const int ty = threadIdx.y;                 // 0..7

    #pragma unroll
    for (int i = 0; i < 32; i += 8) {
        tile[ty + i][tx] = W[(size_t)(hBase + ty + i) * FEAT + fBase + tx];
    }
    __syncthreads();
    #pragma unroll
    for (int i = 0; i < 32; i += 8) {
        WT[(size_t)(fBase + ty + i) * HACC + hBase + tx] = tile[tx][ty + i];
    }
}

// ---------------------------------------------------------------------------
// Fused NNUE forward: one 256-thread block per batch row.
//   Phase A: 32B/side/thread/iter nontemporal scan -> LDS index lists
//   Phase B: sparse accumulate from transposed weights (coalesced 1KB reads),
//            4x unrolled, two partial accumulators
//   Phase C: stm blend + clip + tiny MLP tail, all in LDS
// ---------------------------------------------------------------------------
__global__ __launch_bounds__(256) void nnue_fwd_kernel(
    const float* __restrict__ wfeat, const float* __restrict__ bfeat,
    const float* __restrict__ stm,
    const float* __restrict__ WwT, const float* __restrict__ bw,
    const float* __restrict__ WbT, const float* __restrict__ bb,
    const float* __restrict__ W1, const float* __restrict__ b1,
    const float* __restrict__ W2, const float* __restrict__ b2,
    const float* __restrict__ Wo, const float* __restrict__ bo,
    float* __restrict__ out)
{
    const int row = blockIdx.x;
    const int tid = threadIdx.x;

    __shared__ int   idxW[64], idxB[64];
    __shared__ int   cntW, cntB;
    __shared__ float acc[2 * HACC];
    __shared__ float red[256];
    __shared__ float h1c[H1];
    __shared__ float h2c[H2];

    if (tid == 0) { cntW = 0; cntB = 0; }
    __syncthreads();

    // ---- Phase A: scan 8 floats per side per thread-iteration.
    // Features are 0.0f/1.0f; integer OR detects nonzero.  Common path
    // (per wave-iter): 4 nt dwordx4 loads + ~14 v_or/cmp + 2 ballots, no
    // divergence.  nt keeps the 86MB WT table L3-resident.
    const u32x4* wf4 = (const u32x4*)(wfeat + (size_t)row * FEAT);
    const u32x4* bf4 = (const u32x4*)(bfeat + (size_t)row * FEAT);
    const int F8 = FEAT / 8;  // 5240
    for (int i = tid; i < F8; i += 256) {
        u32x4 v0 = __builtin_nontemporal_load(&wf4[2 * i + 0]);
        u32x4 v1 = __builtin_nontemporal_load(&wf4[2 * i + 1]);
        u32x4 u0 = __builtin_nontemporal_load(&bf4[2 * i + 0]);
        u32x4 u1 = __builtin_nontemporal_load(&bf4[2 * i + 1]);
        const unsigned nzw = (v0.x | v0.y | v0.z | v0.w) | (v1.x | v1.y | v1.z | v1.w);
        const unsigned nzb = (u0.x | u0.y | u0.z | u0.w) | (u1.x | u1.y | u1.z | u1.w);
        if (__any(nzw != 0u)) {
            if (nzw) {
                const int b = 8 * i;
                if (v0.x) { int p = atomicAdd(&cntW, 1); if (p < 64) idxW[p] = b + 0; }
                if (v0.y) { int p = atomicAdd(&cntW, 1); if (p < 64) idxW[p] = b + 1; }
                if (v0.z) { int p = atomicAdd(&cntW, 1); if (p < 64) idxW[p] = b + 2; }
                if (v0.w) { int p = atomicAdd(&cntW, 1); if (p < 64) idxW[p] = b + 3; }
                if (v1.x) { int p = atomicAdd(&cntW, 1); if (p < 64) idxW[p] = b + 4; }
                if (v1.y) { int p = atomicAdd(&cntW, 1); if (p < 64) idxW[p] = b + 5; }
                if (v1.z) { int p = atomicAdd(&cntW, 1); if (p < 64) idxW[p] = b + 6; }
                if (v1.w) { int p = atomicAdd(&cntW, 1); if (p < 64) idxW[p] = b + 7; }
            }
        }
        if (__any(nzb != 0u)) {
            if (nzb) {
                const int b = 8 * i;
                if (u0.x) { int p = atomicAdd(&cntB, 1); if (p < 64) idxB[p] = b + 0; }
                if (u0.y) { int p = atomicAdd(&cntB, 1); if (p < 64) idxB[p] = b + 1; }
                if (u0.z) { int p = atomicAdd(&cntB, 1); if (p < 64) idxB[p] = b + 2; }
                if (u0.w) { int p = atomicAdd(&cntB, 1); if (p < 64) idxB[p] = b + 3; }
                if (u1.x) { int p = atomicAdd(&cntB, 1); if (p < 64) idxB[p] = b + 4; }
                if (u1.y) { int p = atomicAdd(&cntB, 1); if (p < 64) idxB[p] = b + 5; }
                if (u1.z) { int p = atomicAdd(&cntB, 1); if (p < 64) idxB[p] = b + 6; }
                if (u1.w) { int p = atomicAdd(&cntB, 1); if (p < 64) idxB[p] = b + 7; }
            }
        }
    }
    __syncthreads();

    const int nw = min(cntW, 64);
    const int nb = min(cntB, 64);

    // ---- Phase B: sparse accumulate; thread tid owns accumulator element tid.
    // 4x unrolled, 2 partial sums -> 4 independent 1KB loads in flight.
    float accW = bw[tid], accW2 = 0.f;
    float accB = bb[tid], accB2 = 0.f;
    {
        int i = 0;
        for (; i + 4 <= nw; i += 4) {
            float a0 = WwT[(size_t)idxW[i + 0] * HACC + tid];
            float a1 = WwT[(size_t)idxW[i + 1] * HACC + tid];
            float a2 = WwT[(size_t)idxW[i + 2] * HACC + tid];
            float a3 = WwT[(size_t)idxW[i + 3] * HACC + tid];
            accW += a0 + a2; accW2 += a1 + a3;
        }
        for (; i < nw; ++i) accW += WwT[(size_t)idxW[i] * HACC + tid];
        i = 0;
        for (; i + 4 <= nb; i += 4) {
            float a0 = WbT[(size_t)idxB[i + 0] * HACC + tid];
            float a1 = WbT[(size_t)idxB[i + 1] * HACC + tid];
            float a2 = WbT[(size_t)idxB[i + 2] * HACC + tid];
            float a3 = WbT[(size_t)idxB[i + 3] * HACC + tid];
            accB += a0 + a2; accB2 += a1 + a3;
        }
        for (; i < nb; ++i) accB += WbT[(size_t)idxB[i] * HACC + tid];
    }
    const float aW = accW + accW2;
    const float aB = accB + accB2;

    // ---- stm blend (matches reference: blend raw halves, then clip)
    const float s = stm[row];
    const float a0 = (1.f - s) * aW + s * aB;
    const float a1 = (1.f - s) * aB + s * aW;
    acc[tid]        = fminf(fmaxf(a0, 0.f), 1.f);
    acc[HACC + tid] = fminf(fmaxf(a1, 0.f), 1.f);
    __syncthreads();

    // ---- Phase C: tail MLP
    // h1: 32 outputs x 512 inputs; 8 threads per output, 64 elements each
    {
        const int j = tid >> 3;       // output 0..31
        const int p = tid & 7;        // partial 0..7
        const float* w1row = W1 + (size_t)j * (2 * HACC) + p * 64;
        const float* accp  = acc + p * 64;
        float partial = 0.f;
        #pragma unroll 8
        for (int k = 0; k < 64; ++k) partial += accp[k] * w1row[k];
        red[tid] = partial;
    }
    __syncthreads();
    if ((tid & 7) == 0) {
        const int j = tid >> 3;
        float h = b1[j];
        #pragma unroll
        for (int q = 0; q < 8; ++q) h += red[(j << 3) + q];
        h1c[j] = fminf(fmaxf(h, 0.f), 1.f);
    }
    __syncthreads();
    // h2: 32 outputs x 32 inputs
    if (tid < H2) {
        float h = b2[tid];
        const float* w2row = W2 + (size_t)tid * H1;
        #pragma unroll
        for (int k = 0; k < H1; ++k) h += h1c[k] * w2row[k];
        h2c[tid] = fminf(fmaxf(h, 0.f), 1.f);
    }
    __syncthreads();
    // out: 1 x 32
    if (tid == 0) {
        float o = bo[0];
        #pragma unroll
        for (int k = 0; k < H2; ++k) o += h2c[k] * Wo[k];
        out[row] = o;
    }
}

extern "C" void kernel_launch(void* const* d_in, const int* in_sizes, int n_in,
                              void* d_out, int out_size, void* d_ws, size_t ws_size,
                              hipStream_t stream)
{
    const float* wfeat = (const float*)d_in[0];
    const float* bfeat = (const float*)d_in[1];
    const float* stm   = (const float*)d_in[2];
    const float* Ww    = (const float*)d_in[3];
    const float* bw    = (const float*)d_in[4];
    const float* Wb    = (const float*)d_in[5];
    const float* bb    = (const float*)d_in[6];
    const float* W1    = (const float*)d_in[7];
    const float* b1    = (const float*)d_in[8];
    const float* W2    = (const float*)d_in[9];
    const float* b2    = (const float*)d_in[10];
    const float* Wo    = (const float*)d_in[11];
    const float* bo    = (const float*)d_in[12];
    float* out = (float*)d_out;

    float* WwT = (float*)d_ws;
    float* WbT = WwT + (size_t)FEAT * HACC;
    dim3 tgrid(FEAT / 32, HACC / 32, 2);
    dim3 tblk(32, 8);
    transpose_kernel<<<tgrid, tblk, 0, stream>>>(Ww, WwT, Wb, WbT);
    nnue_fwd_kernel<<<BATCH, 256, 0, stream>>>(
        wfeat, bfeat, stm, WwT, bw, WbT, bb, W1, b1, W2, b2, Wo, bo, out);
}